// Round 10
// baseline (562.220 us; speedup 1.0000x reference)
//
#include <hip/hip_runtime.h>
#include <hip/hip_bf16.h>
#include <stdint.h>

#define HID 128
#define BSHIFT 7
#define NBLK 64      // edge-slice blocks for count/place

typedef __attribute__((ext_vector_type(8))) __bf16 bf16x8;
typedef __attribute__((ext_vector_type(4))) float f32x4;
typedef __attribute__((ext_vector_type(2))) float f32x2;

static __device__ __forceinline__ float bf2f(ushort h){
  union { uint u; float f; } c; c.u = ((uint)h) << 16; return c.f;
}
static __device__ __forceinline__ float u2f(uint u){
  union { uint u; float f; } c; c.u = u; return c.f;
}
static __device__ __forceinline__ ushort f2bf(float f){
  union { float f; uint u; } c; c.f = f;
  uint u = c.u;
  return (ushort)((u + 0x7fffu + ((u >> 16) & 1u)) >> 16);
}
static __device__ __forceinline__ bf16x8 load8(const ushort* p){
  return *(const bf16x8*)p;
}

// ---------------- f32 -> bf16 convert (emb) ----------------
__global__ void k_cvt(const float* __restrict__ in, ushort* __restrict__ out, int n){
  int i = blockIdx.x * 256 + threadIdx.x;
  if (i < n) out[i] = f2bf(in[i]);
}

// ---- layer weights f32 -> bf16 frag-major: [layer][kt4][mat2][jt8][lane64][e8] ----
// Column permutation: out col = l16*8 + jt -> dense 16B stores in epilogue.
__global__ void k_cvtw(const float* __restrict__ Wl, const float* __restrict__ Wr,
                       ushort* __restrict__ outF, int total){
  int o = blockIdx.x * 256 + threadIdx.x;
  if (o >= total) return;
  int layer = o >> 15;
  int r = o & 32767;
  int e    = r & 7;
  int lane = (r >> 3) & 63;
  int jt   = (r >> 9) & 7;
  int mat  = (r >> 12) & 1;
  int kt   = r >> 13;
  int l16 = lane & 15, quad = lane >> 4;
  int j = l16 * 8 + jt;               // permuted output column
  int k = kt * 32 + quad * 8 + e;
  const float* W = mat ? Wr : Wl;
  outF[o] = f2bf(W[layer * 16384 + j * 128 + k]);
}

// ---- jk weights f32 -> bf16 frag-major: [kt16][jt8][lane64][e8] ----
// col = l16*4 + (jt&3) + (jt>>2)*64 -> two dense dwordx4 stores per row.
__global__ void k_cvtjk(const float* __restrict__ jkW, ushort* __restrict__ outF){
  int o = blockIdx.x * 256 + threadIdx.x;   // total 65536
  int e    = o & 7;
  int lane = (o >> 3) & 63;
  int jt   = (o >> 9) & 7;
  int kt   = o >> 12;
  int l16 = lane & 15, quad = lane >> 4;
  int j = l16 * 4 + (jt & 3) + (jt >> 2) * 64;   // permuted output column
  int k = kt * 32 + quad * 8 + e;
  outF[o] = f2bf(jkW[j * 512 + k]);
}

// ================ deterministic two-level CSR build (no global atomics) ================
__global__ __launch_bounds__(1024) void k_count(
    const int* __restrict__ dst, int* __restrict__ rowcnt, int E, int NB, int es){
  __shared__ int h[1024];
  int blk = blockIdx.x;
  for (int i = threadIdx.x; i < NB; i += 1024) h[i] = 0;
  __syncthreads();
  int e0 = blk * es, e1 = min(e0 + es, E);
  for (int e = e0 + threadIdx.x; e < e1; e += 1024)
    atomicAdd(&h[dst[e] >> BSHIFT], 1);
  __syncthreads();
  for (int i = threadIdx.x; i < NB; i += 1024)
    rowcnt[blk * NB + i] = h[i];
}

__global__ __launch_bounds__(1024) void k_colscan(
    int* __restrict__ rowcnt, int* __restrict__ bbase, int NB, int nblk){
  int b = threadIdx.x;
  int total = 0;
  if (b < NB)
    for (int r = 0; r < nblk; r++) total += rowcnt[r * NB + b];
  int lane = b & 63, w = b >> 6;
  int x = total;
  #pragma unroll
  for (int d = 1; d < 64; d <<= 1){ int y = __shfl_up(x, d, 64); if (lane >= d) x += y; }
  __shared__ int tmp[16];
  if (lane == 63) tmp[w] = x;
  __syncthreads();
  if (b < 64){
    int s = (lane < 16) ? tmp[lane] : 0;
    #pragma unroll
    for (int d = 1; d < 16; d <<= 1){ int y = __shfl_up(s, d, 64); if (lane >= d) s += y; }
    if (lane < 16) tmp[lane] = s;
  }
  __syncthreads();
  int base = ((w > 0) ? tmp[w - 1] : 0) + x - total;  // exclusive
  if (b < NB){
    bbase[b] = base;
    int acc = base;
    for (int r = 0; r < nblk; r++){
      int v = rowcnt[r * NB + b];
      rowcnt[r * NB + b] = acc;
      acc += v;
    }
    if (b == NB - 1) bbase[NB] = acc;
  }
}

__global__ __launch_bounds__(1024) void k_place(
    const int* __restrict__ src, const int* __restrict__ dst,
    const int* __restrict__ rowcnt, uint* __restrict__ binned, int E, int NB, int es){
  __shared__ int cur[1024];
  int blk = blockIdx.x;
  for (int i = threadIdx.x; i < NB; i += 1024) cur[i] = rowcnt[blk * NB + i];
  __syncthreads();
  int e0 = blk * es, e1 = min(e0 + es, E);
  for (int e = e0 + threadIdx.x; e < e1; e += 1024){
    int d = dst[e];
    int b = d >> BSHIFT;
    int pos = atomicAdd(&cur[b], 1);
    binned[pos] = ((uint)src[e] << BSHIFT) | (uint)(d & 127);
  }
}

__global__ __launch_bounds__(256) void k_bpass(
    const uint* __restrict__ binned, const int* __restrict__ bbase,
    int* __restrict__ csr, int* __restrict__ offs, int* __restrict__ cnt, int N){
  int b = blockIdx.x;
  int n0 = b << BSHIFT;
  int tid = threadIdx.x;
  __shared__ int lcnt[128], loffs[128];
  if (tid < 128) lcnt[tid] = 0;
  __syncthreads();
  int base = bbase[b];
  int m = bbase[b + 1] - base;
  const uint* bp = binned + base;
  uint vv[12]; int slot[12];
  #pragma unroll
  for (int u = 0; u < 12; u++){
    int i = tid + u * 256;
    if (i < m){
      uint v = bp[i];
      vv[u] = v;
      slot[u] = atomicAdd(&lcnt[v & 127], 1);
    }
  }
  __syncthreads();
  if (tid < 64){
    int a0 = lcnt[tid * 2], a1 = lcnt[tid * 2 + 1];
    int s = a0 + a1;
    int x = s;
    #pragma unroll
    for (int d = 1; d < 64; d <<= 1){ int y = __shfl_up(x, d, 64); if (tid >= d) x += y; }
    int excl = x - s;
    loffs[tid * 2] = excl;
    loffs[tid * 2 + 1] = excl + a0;
  }
  __syncthreads();
  if (tid < 128 && n0 + tid < N){
    cnt[n0 + tid] = lcnt[tid];
    offs[n0 + tid] = base + loffs[tid];
  }
  #pragma unroll
  for (int u = 0; u < 12; u++){
    int i = tid + u * 256;
    if (i < m){
      uint v = vv[u];
      csr[base + loffs[v & 127] + slot[u]] = (int)(v >> BSHIFT);
    }
  }
}

// ---------------- scatter-mean aggregation v5 (kept; measured neutral vs v4,
// fewer instructions). Pattern-BW-bound at ~3.5 TB/s -- accepted floor. -------
__global__ __launch_bounds__(256) void k_aggregate(
    const ushort* __restrict__ x, const int* __restrict__ csr,
    const int* __restrict__ offs, const int* __restrict__ cnt,
    ushort* __restrict__ agg, int N){
  int node = blockIdx.x * 4 + (threadIdx.x >> 6);
  int lane = threadIdx.x & 63;
  if (node >= N) return;
  int grp = lane >> 4;       // which edge of the 4-group
  int l16 = lane & 15;       // 16B chunk within the row (8 features)
  uint lb  = (uint)(l16 << 4);
  int beg = offs[node], d = cnt[node];
  if (d == 0){
    if (grp == 0){
      uint4 z = {0u, 0u, 0u, 0u};
      *(uint4*)(agg + (size_t)node * HID + l16 * 8) = z;
    }
    return;
  }
  const int* __restrict__ cp = csr + beg;
  const char* __restrict__ xb = (const char*)x;
  f32x2 s0 = {0.f,0.f}, s1 = {0.f,0.f}, s2 = {0.f,0.f}, s3 = {0.f,0.f};
  int i = 0;
  for (; i + 8 <= d; i += 8){
    uint o0 = ((uint)cp[i + grp] << 8) + lb;
    uint o1 = ((uint)cp[i + 4 + grp] << 8) + lb;
    uint4 v0 = *(const uint4*)(xb + o0);
    uint4 v1 = *(const uint4*)(xb + o1);
    f32x2 t;
    t.x = u2f(v0.x << 16); t.y = u2f(v0.x & 0xffff0000u); s0 += t;
    t.x = u2f(v0.y << 16); t.y = u2f(v0.y & 0xffff0000u); s1 += t;
    t.x = u2f(v0.z << 16); t.y = u2f(v0.z & 0xffff0000u); s2 += t;
    t.x = u2f(v0.w << 16); t.y = u2f(v0.w & 0xffff0000u); s3 += t;
    t.x = u2f(v1.x << 16); t.y = u2f(v1.x & 0xffff0000u); s0 += t;
    t.x = u2f(v1.y << 16); t.y = u2f(v1.y & 0xffff0000u); s1 += t;
    t.x = u2f(v1.z << 16); t.y = u2f(v1.z & 0xffff0000u); s2 += t;
    t.x = u2f(v1.w << 16); t.y = u2f(v1.w & 0xffff0000u); s3 += t;
  }
  if (i < d){
    int p0 = i + grp, p1 = i + 4 + grp;
    bool k0 = p0 < d, k1 = p1 < d;
    uint o0 = ((uint)cp[k0 ? p0 : d - 1] << 8) + lb;
    uint o1 = ((uint)cp[k1 ? p1 : d - 1] << 8) + lb;
    uint4 v0 = *(const uint4*)(xb + o0);
    uint4 v1 = *(const uint4*)(xb + o1);
    uint ax, ay, az, aw;
    ax = k0 ? v0.x : 0u; ay = k0 ? v0.y : 0u; az = k0 ? v0.z : 0u; aw = k0 ? v0.w : 0u;
    f32x2 t;
    t.x = u2f(ax << 16); t.y = u2f(ax & 0xffff0000u); s0 += t;
    t.x = u2f(ay << 16); t.y = u2f(ay & 0xffff0000u); s1 += t;
    t.x = u2f(az << 16); t.y = u2f(az & 0xffff0000u); s2 += t;
    t.x = u2f(aw << 16); t.y = u2f(aw & 0xffff0000u); s3 += t;
    ax = k1 ? v1.x : 0u; ay = k1 ? v1.y : 0u; az = k1 ? v1.z : 0u; aw = k1 ? v1.w : 0u;
    t.x = u2f(ax << 16); t.y = u2f(ax & 0xffff0000u); s0 += t;
    t.x = u2f(ay << 16); t.y = u2f(ay & 0xffff0000u); s1 += t;
    t.x = u2f(az << 16); t.y = u2f(az & 0xffff0000u); s2 += t;
    t.x = u2f(aw << 16); t.y = u2f(aw & 0xffff0000u); s3 += t;
  }
  #pragma unroll
  for (int m = 16; m < 64; m <<= 1){
    s0.x += __shfl_xor(s0.x, m, 64); s0.y += __shfl_xor(s0.y, m, 64);
    s1.x += __shfl_xor(s1.x, m, 64); s1.y += __shfl_xor(s1.y, m, 64);
    s2.x += __shfl_xor(s2.x, m, 64); s2.y += __shfl_xor(s2.y, m, 64);
    s3.x += __shfl_xor(s3.x, m, 64); s3.y += __shfl_xor(s3.y, m, 64);
  }
  if (grp == 0){
    float inv = 1.0f / fmaxf((float)d, 1.0f);
    uint4 o;
    o.x = (uint)f2bf(s0.x * inv) | ((uint)f2bf(s0.y * inv) << 16);
    o.y = (uint)f2bf(s1.x * inv) | ((uint)f2bf(s1.y * inv) << 16);
    o.z = (uint)f2bf(s2.x * inv) | ((uint)f2bf(s2.y * inv) << 16);
    o.w = (uint)f2bf(s3.x * inv) | ((uint)f2bf(s3.y * inv) << 16);
    *(uint4*)(agg + (size_t)node * HID + l16 * 8) = o;
  }
}

// ---------------- fused dual-GEMM + bias + LN + ReLU + residual (layers 0,1) ----------------
template<int HAS_RES>
__global__ __launch_bounds__(256, 4) void k_layer(
    const ushort* __restrict__ agg, const ushort* __restrict__ xin,
    const ushort* __restrict__ Wf,     // [kt4][mat2][jt8][lane64][8] bf16 (col-permuted)
    const float* __restrict__ bl, const float* __restrict__ gamma,
    const float* __restrict__ beta,
    ushort* __restrict__ xout, int N){
  int tid = threadIdx.x;
  int wv = tid >> 6, lane = tid & 63;
  int quad = lane >> 4, l16 = lane & 15;
  int rowbase = blockIdx.x * 128 + wv * 32;
  int r0 = rowbase + l16;      if (r0 >= N) r0 = N - 1;
  int r1 = rowbase + 16 + l16; if (r1 >= N) r1 = N - 1;
  int aq = quad * 8;

  const ushort* pa0 = agg + (size_t)r0 * HID;
  const ushort* pa1 = agg + (size_t)r1 * HID;
  const ushort* px0 = xin + (size_t)r0 * HID;
  const ushort* px1 = xin + (size_t)r1 * HID;

  f32x4 acc[2][8];
  {
    float4 bi0 = *(const float4*)(bl + l16 * 8);
    float4 bi1 = *(const float4*)(bl + l16 * 8 + 4);
    float bia[8] = {bi0.x, bi0.y, bi0.z, bi0.w, bi1.x, bi1.y, bi1.z, bi1.w};
    #pragma unroll
    for (int jt = 0; jt < 8; jt++){
      float b = bia[jt];
      f32x4 c = {b, b, b, b};
      acc[0][jt] = c; acc[1][jt] = c;
    }
  }

  bf16x8 c0 = load8(pa0 + aq), c1 = load8(pa1 + aq);
  bf16x8 c2 = load8(px0 + aq), c3 = load8(px1 + aq);
  #pragma unroll
  for (int kt = 0; kt < 4; kt++){
    bf16x8 n0 = c0, n1 = c1, n2 = c2, n3 = c3;
    if (kt < 3){
      int ao = (kt + 1) * 32 + aq;
      n0 = load8(pa0 + ao); n1 = load8(pa1 + ao);
      n2 = load8(px0 + ao); n3 = load8(px1 + ao);
    }
    #pragma unroll
    for (int jt = 0; jt < 8; jt++){
      bf16x8 bL = load8(Wf + ((kt * 16 + jt) * 64 + lane) * 8);
      bf16x8 bR = load8(Wf + ((kt * 16 + 8 + jt) * 64 + lane) * 8);
      acc[0][jt] = __builtin_amdgcn_mfma_f32_16x16x32_bf16(c0, bL, acc[0][jt], 0, 0, 0);
      acc[1][jt] = __builtin_amdgcn_mfma_f32_16x16x32_bf16(c1, bL, acc[1][jt], 0, 0, 0);
      acc[0][jt] = __builtin_amdgcn_mfma_f32_16x16x32_bf16(c2, bR, acc[0][jt], 0, 0, 0);
      acc[1][jt] = __builtin_amdgcn_mfma_f32_16x16x32_bf16(c3, bR, acc[1][jt], 0, 0, 0);
    }
    c0 = n0; c1 = n1; c2 = n2; c3 = n3;
  }

  float4 g0 = *(const float4*)(gamma + l16 * 8);
  float4 g1 = *(const float4*)(gamma + l16 * 8 + 4);
  float4 be0 = *(const float4*)(beta + l16 * 8);
  float4 be1 = *(const float4*)(beta + l16 * 8 + 4);
  float gg[8] = {g0.x, g0.y, g0.z, g0.w, g1.x, g1.y, g1.z, g1.w};
  float bb[8] = {be0.x, be0.y, be0.z, be0.w, be1.x, be1.y, be1.z, be1.w};

  #pragma unroll
  for (int rt = 0; rt < 2; rt++){
    float s1[4] = {0,0,0,0}, s2[4] = {0,0,0,0};
    #pragma unroll
    for (int jt = 0; jt < 8; jt++){
      #pragma unroll
      for (int r = 0; r < 4; r++){ float v = acc[rt][jt][r]; s1[r] += v; s2[r] += v * v; }
    }
    #pragma unroll
    for (int m = 1; m < 16; m <<= 1){
      #pragma unroll
      for (int r = 0; r < 4; r++){
        s1[r] += __shfl_xor(s1[r], m, 64);
        s2[r] += __shfl_xor(s2[r], m, 64);
      }
    }
    #pragma unroll
    for (int r = 0; r < 4; r++){
      float mu = s1[r] * (1.f / 128.f);
      float var = s2[r] * (1.f / 128.f) - mu * mu;
      float rs = rsqrtf(var + 1e-5f);
      int row = rowbase + rt * 16 + quad * 4 + r;
      int rowc = row < N ? row : N - 1;
      uint rw[4] = {0u, 0u, 0u, 0u};
      if (HAS_RES){
        uint4 rv = *(const uint4*)(xin + (size_t)rowc * HID + l16 * 8);
        rw[0] = rv.x; rw[1] = rv.y; rw[2] = rv.z; rw[3] = rv.w;
      }
      uint ow[4];
      #pragma unroll
      for (int p = 0; p < 4; p++){
        float v0 = (acc[rt][2 * p][r] - mu) * rs * gg[2 * p] + bb[2 * p];
        float v1 = (acc[rt][2 * p + 1][r] - mu) * rs * gg[2 * p + 1] + bb[2 * p + 1];
        v0 = fmaxf(v0, 0.f);
        v1 = fmaxf(v1, 0.f);
        if (HAS_RES){
          v0 += bf2f((ushort)(rw[p] & 0xffffu));
          v1 += bf2f((ushort)(rw[p] >> 16));
        }
        ow[p] = (uint)f2bf(v0) | ((uint)f2bf(v1) << 16);
      }
      uint4 o;
      o.x = ow[0]; o.y = ow[1]; o.z = ow[2]; o.w = ow[3];
      if (row < N)
        *(uint4*)(xout + (size_t)row * HID + l16 * 8) = o;
    }
  }
}

// ======== FUSED layer-2 + JK: x3 never touches HBM ========
// Layer phase identical to k_layer<1>; epilogue writes x3 tile to a swizzled
// 32KB LDS buffer (unconditionally -- rows>=N hold finite garbage, outputs
// guarded). Each wave reads back ONLY its own 32 rows as JK A-frags ->
// same-wave LDS ordering, zero barriers (the R7-verified hand-off). JK's
// emb/x1/x2 A-frags from global (x2 L2-warm), weights from L2. Saves the
// 51MB x3 HBM round-trip + one launch.
__global__ __launch_bounds__(256, 4) void k_layerjk(
    const ushort* __restrict__ agg, const ushort* __restrict__ xin,   // xin = x2
    const ushort* __restrict__ emb, const ushort* __restrict__ x1,
    const ushort* __restrict__ Wf,    // layer2 weights (col-permuted)
    const ushort* __restrict__ Wjk,   // jk weights (col-permuted)
    const float* __restrict__ bl, const float* __restrict__ gamma,
    const float* __restrict__ beta, const float* __restrict__ jkb,
    float* __restrict__ out, int N){
  __shared__ ushort sX[16384];        // 32KB x3 tile, XOR-swizzled rows
  int tid = threadIdx.x;
  int wv = tid >> 6, lane = tid & 63;
  int quad = lane >> 4, l16 = lane & 15;
  int rowbase = blockIdx.x * 128 + wv * 32;
  int r0 = rowbase + l16;      if (r0 >= N) r0 = N - 1;
  int r1 = rowbase + 16 + l16; if (r1 >= N) r1 = N - 1;
  int aq = quad * 8;
  char* __restrict__ sXb = (char*)sX;

  const ushort* pa0 = agg + (size_t)r0 * HID;
  const ushort* pa1 = agg + (size_t)r1 * HID;
  const ushort* px0 = xin + (size_t)r0 * HID;
  const ushort* px1 = xin + (size_t)r1 * HID;

  // ---- layer-2 phase ----
  f32x4 acc[2][8];
  {
    float4 bi0 = *(const float4*)(bl + l16 * 8);
    float4 bi1 = *(const float4*)(bl + l16 * 8 + 4);
    float bia[8] = {bi0.x, bi0.y, bi0.z, bi0.w, bi1.x, bi1.y, bi1.z, bi1.w};
    #pragma unroll
    for (int jt = 0; jt < 8; jt++){
      float b = bia[jt];
      f32x4 c = {b, b, b, b};
      acc[0][jt] = c; acc[1][jt] = c;
    }
  }

  bf16x8 c0 = load8(pa0 + aq), c1 = load8(pa1 + aq);
  bf16x8 c2 = load8(px0 + aq), c3 = load8(px1 + aq);
  #pragma unroll
  for (int kt = 0; kt < 4; kt++){
    bf16x8 n0 = c0, n1 = c1, n2 = c2, n3 = c3;
    if (kt < 3){
      int ao = (kt + 1) * 32 + aq;
      n0 = load8(pa0 + ao); n1 = load8(pa1 + ao);
      n2 = load8(px0 + ao); n3 = load8(px1 + ao);
    }
    #pragma unroll
    for (int jt = 0; jt < 8; jt++){
      bf16x8 bL = load8(Wf + ((kt * 16 + jt) * 64 + lane) * 8);
      bf16x8 bR = load8(Wf + ((kt * 16 + 8 + jt) * 64 + lane) * 8);
      acc[0][jt] = __builtin_amdgcn_mfma_f32_16x16x32_bf16(c0, bL, acc[0][jt], 0, 0, 0);
      acc[1][jt] = __builtin_amdgcn_mfma_f32_16x16x32_bf16(c1, bL, acc[1][jt], 0, 0, 0);
      acc[0][jt] = __builtin_amdgcn_mfma_f32_16x16x32_bf16(c2, bR, acc[0][jt], 0, 0, 0);
      acc[1][jt] = __builtin_amdgcn_mfma_f32_16x16x32_bf16(c3, bR, acc[1][jt], 0, 0, 0);
    }
    c0 = n0; c1 = n1; c2 = n2; c3 = n3;
  }

  // ---- epilogue: LN + ReLU + residual -> x3 tile in LDS (swizzled) ----
  {
    float4 g0 = *(const float4*)(gamma + l16 * 8);
    float4 g1 = *(const float4*)(gamma + l16 * 8 + 4);
    float4 be0 = *(const float4*)(beta + l16 * 8);
    float4 be1 = *(const float4*)(beta + l16 * 8 + 4);
    float gg[8] = {g0.x, g0.y, g0.z, g0.w, g1.x, g1.y, g1.z, g1.w};
    float bb[8] = {be0.x, be0.y, be0.z, be0.w, be1.x, be1.y, be1.z, be1.w};

    #pragma unroll
    for (int rt = 0; rt < 2; rt++){
      float s1[4] = {0,0,0,0}, s2[4] = {0,0,0,0};
      #pragma unroll
      for (int jt = 0; jt < 8; jt++){
        #pragma unroll
        for (int r = 0; r < 4; r++){ float v = acc[rt][jt][r]; s1[r] += v; s2[r] += v * v; }
      }
      #pragma unroll
      for (int m = 1; m < 16; m <<= 1){
        #pragma unroll
        for (int r = 0; r < 4; r++){
          s1[r] += __shfl_xor(s1[r], m, 64);
          s2[r] += __shfl_xor(s2[r], m, 64);
        }
      }
      #pragma unroll
      for (int r = 0; r < 4; r++){
        float mu = s1[r] * (1.f / 128.f);
        float var = s2[r] * (1.f / 128.f) - mu * mu;
        float rs = rsqrtf(var + 1e-5f);
        int row = rowbase + rt * 16 + quad * 4 + r;
        int rowc = row < N ? row : N - 1;
        uint4 rv = *(const uint4*)(xin + (size_t)rowc * HID + l16 * 8);
        uint rw[4] = {rv.x, rv.y, rv.z, rv.w};
        uint ow[4];
        #pragma unroll
        for (int p = 0; p < 4; p++){
          float v0 = (acc[rt][2 * p][r] - mu) * rs * gg[2 * p] + bb[2 * p];
          float v1 = (acc[rt][2 * p + 1][r] - mu) * rs * gg[2 * p + 1] + bb[2 * p + 1];
          v0 = fmaxf(v0, 0.f) + bf2f((ushort)(rw[p] & 0xffffu));
          v1 = fmaxf(v1, 0.f) + bf2f((ushort)(rw[p] >> 16));
          ow[p] = (uint)f2bf(v0) | ((uint)f2bf(v1) << 16);
        }
        uint4 o;
        o.x = ow[0]; o.y = ow[1]; o.z = ow[2]; o.w = ow[3];
        // unconditional LDS store (this wave's own row)
        uint lrow = (uint)(wv * 32 + rt * 16 + quad * 4 + r);
        uint wo = (lrow << 8) + ((uint)(l16 * 16) ^ ((lrow & 7) << 4));
        *(uint4*)(sXb + wo) = o;
      }
    }
  }
  // no barrier: each wave reads back only its own rows

  // ---- JK phase: acc reused, A from {emb, x1, xin(global), sX(LDS)} ----
  f32x4 accj[2][8];
  #pragma unroll
  for (int jt = 0; jt < 8; jt++){
    f32x4 z = {0.f, 0.f, 0.f, 0.f};
    accj[0][jt] = z; accj[1][jt] = z;
  }

  size_t o0 = (size_t)r0 * HID, o1 = (size_t)r1 * HID;
  const ushort* srcs[3] = {emb, x1, xin};
  bf16x8 a0 = load8(emb + o0 + aq);
  bf16x8 a1 = load8(emb + o1 + aq);
  #pragma unroll
  for (int ktg = 0; ktg < 12; ktg++){       // global sources: emb, x1, x2
    bf16x8 n0 = a0, n1 = a1;
    if (ktg < 11){
      const ushort* sp = srcs[(ktg + 1) >> 2];
      int ao = ((ktg + 1) & 3) * 32 + aq;
      n0 = load8(sp + o0 + ao);
      n1 = load8(sp + o1 + ao);
    }
    #pragma unroll
    for (int jt = 0; jt < 8; jt++){
      bf16x8 bW = load8(Wjk + ((ktg * 8 + jt) * 64 + lane) * 8);
      accj[0][jt] = __builtin_amdgcn_mfma_f32_16x16x32_bf16(a0, bW, accj[0][jt], 0, 0, 0);
      accj[1][jt] = __builtin_amdgcn_mfma_f32_16x16x32_bf16(a1, bW, accj[1][jt], 0, 0, 0);
    }
    a0 = n0; a1 = n1;
  }
  // x3 from LDS (kt groups 12..15)
  {
    int lr0 = wv * 32 + l16, lr1 = lr0 + 16;
    #pragma unroll
    for (int kt = 0; kt < 4; kt++){
      uint bo = (uint)(kt * 64 + quad * 16);
      bf16x8 aL0 = *(const bf16x8*)(sXb + ((uint)lr0 << 8) + (bo ^ ((uint)(lr0 & 7) << 4)));
      bf16x8 aL1 = *(const bf16x8*)(sXb + ((uint)lr1 << 8) + (bo ^ ((uint)(lr1 & 7) << 4)));
      int ktg = 12 + kt;
      #pragma unroll
      for (int jt = 0; jt < 8; jt++){
        bf16x8 bW = load8(Wjk + ((ktg * 8 + jt) * 64 + lane) * 8);
        accj[0][jt] = __builtin_amdgcn_mfma_f32_16x16x32_bf16(aL0, bW, accj[0][jt], 0, 0, 0);
        accj[1][jt] = __builtin_amdgcn_mfma_f32_16x16x32_bf16(aL1, bW, accj[1][jt], 0, 0, 0);
      }
    }
  }

  // ---- JK epilogue: bias + f32 stores ----
  float4 jb0 = *(const float4*)(jkb + l16 * 4);
  float4 jb1 = *(const float4*)(jkb + 64 + l16 * 4);
  float bia[8] = {jb0.x, jb0.y, jb0.z, jb0.w, jb1.x, jb1.y, jb1.z, jb1.w};

  #pragma unroll
  for (int rt = 0; rt < 2; rt++){
    #pragma unroll
    for (int r = 0; r < 4; r++){
      int row = rowbase + rt * 16 + quad * 4 + r;
      if (row < N){
        f32x4 v0 = {accj[rt][0][r] + bia[0], accj[rt][1][r] + bia[1],
                    accj[rt][2][r] + bia[2], accj[rt][3][r] + bia[3]};
        f32x4 v1 = {accj[rt][4][r] + bia[4], accj[rt][5][r] + bia[5],
                    accj[rt][6][r] + bia[6], accj[rt][7][r] + bia[7]};
        *(f32x4*)(out + (size_t)row * HID + l16 * 4) = v0;
        *(f32x4*)(out + (size_t)row * HID + 64 + l16 * 4) = v1;
      }
    }
  }
}

extern "C" void kernel_launch(void* const* d_in, const int* in_sizes, int n_in,
                              void* d_out, int out_size, void* d_ws, size_t ws_size,
                              hipStream_t stream){
  const float* emb   = (const float*)d_in[0];
  const float* Wl    = (const float*)d_in[1];
  const float* bl    = (const float*)d_in[2];
  const float* Wr    = (const float*)d_in[3];
  const float* gamma = (const float*)d_in[4];
  const float* beta  = (const float*)d_in[5];
  const float* jkW   = (const float*)d_in[6];
  const float* jkb   = (const float*)d_in[7];
  const int*   eidx  = (const int*)d_in[8];
  int N = in_sizes[0] / HID;
  int E = in_sizes[8] / 2;
  const int* src = eidx;
  const int* dst = eidx + E;
  float* out = (float*)d_out;

  int NB = (N + 127) >> BSHIFT;        // coarse buckets of 128 nodes
  int es = (E + NBLK - 1) / NBLK;      // edges per slice block

  // workspace carve (256B aligned)
  char* w = (char*)d_ws;
  auto carve = [&](size_t bytes) -> char* {
    char* p = w; w += (bytes + 255) & ~(size_t)255; return p;
  };
  int Npad = ((N + 127) / 128) * 128;
  int* rowcnt   = (int*)carve((size_t)NBLK * NB * 4);
  int* bbase    = (int*)carve((size_t)(NB + 1) * 4);
  uint* binned  = (uint*)carve((size_t)E * 4);
  int* cnt      = (int*)carve((size_t)N * 4);
  int* offs     = (int*)carve((size_t)N * 4);
  int* csr      = (int*)carve((size_t)E * 4);
  ushort* Wfrag = (ushort*)carve((size_t)3 * 32768 * 2);
  ushort* jkWf  = (ushort*)carve((size_t)65536 * 2);
  ushort* embbf = (ushort*)carve((size_t)Npad * HID * 2);
  ushort* agg   = (ushort*)carve((size_t)Npad * HID * 2);
  ushort* x1    = (ushort*)carve((size_t)Npad * HID * 2);
  ushort* x2    = (ushort*)carve((size_t)Npad * HID * 2);

  // weight transforms + emb cast
  int nEmb = N * HID;
  k_cvtw<<<(3 * 32768 + 255) / 256, 256, 0, stream>>>(Wl, Wr, Wfrag, 3 * 32768);
  k_cvtjk<<<65536 / 256, 256, 0, stream>>>(jkW, jkWf);
  k_cvt<<<(nEmb + 255) / 256, 256, 0, stream>>>(emb, embbf, nEmb);

  // deterministic two-level CSR build
  k_count<<<NBLK, 1024, 0, stream>>>(dst, rowcnt, E, NB, es);
  k_colscan<<<1, 1024, 0, stream>>>(rowcnt, bbase, NB, NBLK);
  k_place<<<NBLK, 1024, 0, stream>>>(src, dst, rowcnt, binned, E, NB, es);
  k_bpass<<<NB, 256, 0, stream>>>(binned, bbase, csr, offs, cnt, N);

  int aggBlocks = (N + 3) / 4;
  int gemmBlocks = (N + 127) / 128;   // one 128-row tile per block

  // layer 0 (no residual)
  k_aggregate<<<aggBlocks, 256, 0, stream>>>(embbf, csr, offs, cnt, agg, N);
  k_layer<0><<<gemmBlocks, 256, 0, stream>>>(agg, embbf, Wfrag, bl, gamma, beta, x1, N);
  // layer 1
  k_aggregate<<<aggBlocks, 256, 0, stream>>>(x1, csr, offs, cnt, agg, N);
  k_layer<1><<<gemmBlocks, 256, 0, stream>>>(agg, x1, Wfrag + 32768, bl + HID,
                                             gamma + HID, beta + HID, x2, N);
  // layer 2 fused with jumping-knowledge projection (x3 never hits HBM)
  k_aggregate<<<aggBlocks, 256, 0, stream>>>(x2, csr, offs, cnt, agg, N);
  k_layerjk<<<gemmBlocks, 256, 0, stream>>>(agg, x2, embbf, x1,
      Wfrag + 2 * 32768, jkWf, bl + 2 * HID, gamma + 2 * HID, beta + 2 * HID,
      jkb, out, N);
}

// Round 11
// 516.170 us; speedup vs baseline: 1.0892x; 1.0892x over previous
//
#include <hip/hip_runtime.h>
#include <hip/hip_bf16.h>
#include <stdint.h>

#define HID 128
#define BSHIFT 7
#define NBLK 64      // edge-slice blocks for count/place

typedef __attribute__((ext_vector_type(8))) __bf16 bf16x8;
typedef __attribute__((ext_vector_type(4))) float f32x4;
typedef __attribute__((ext_vector_type(2))) float f32x2;

static __device__ __forceinline__ float bf2f(ushort h){
  union { uint u; float f; } c; c.u = ((uint)h) << 16; return c.f;
}
static __device__ __forceinline__ float u2f(uint u){
  union { uint u; float f; } c; c.u = u; return c.f;
}
static __device__ __forceinline__ ushort f2bf(float f){
  union { float f; uint u; } c; c.f = f;
  uint u = c.u;
  return (ushort)((u + 0x7fffu + ((u >> 16) & 1u)) >> 16);
}
static __device__ __forceinline__ bf16x8 load8(const ushort* p){
  return *(const bf16x8*)p;
}

// ---------- merged convert kernel: layer weights + jk weights + emb ----------
// Layer weights frag-major [layer][kt4][mat2][jt8][lane64][e8], col j = l16*8+jt.
// JK weights frag-major [kt16][jt8][lane64][e8], col j = l16*4+(jt&3)+(jt>>2)*64.
__global__ void k_cvtall(const float* __restrict__ emb, const float* __restrict__ Wl,
                         const float* __restrict__ Wr, const float* __restrict__ jkW,
                         ushort* __restrict__ embbf, ushort* __restrict__ Wfrag,
                         ushort* __restrict__ jkWf, int nEmb){
  int o = blockIdx.x * 256 + threadIdx.x;
  if (o < 98304){
    int layer = o >> 15;
    int r = o & 32767;
    int e    = r & 7;
    int lane = (r >> 3) & 63;
    int jt   = (r >> 9) & 7;
    int mat  = (r >> 12) & 1;
    int kt   = r >> 13;
    int l16 = lane & 15, quad = lane >> 4;
    int j = l16 * 8 + jt;
    int k = kt * 32 + quad * 8 + e;
    const float* W = mat ? Wr : Wl;
    Wfrag[o] = f2bf(W[layer * 16384 + j * 128 + k]);
  } else if (o < 163840){
    int q = o - 98304;
    int e    = q & 7;
    int lane = (q >> 3) & 63;
    int jt   = (q >> 9) & 7;
    int kt   = q >> 12;
    int l16 = lane & 15, quad = lane >> 4;
    int j = l16 * 4 + (jt & 3) + (jt >> 2) * 64;
    int k = kt * 32 + quad * 8 + e;
    jkWf[q] = f2bf(jkW[j * 512 + k]);
  } else {
    int q = o - 163840;
    if (q < nEmb) embbf[q] = f2bf(emb[q]);
  }
}

// ================ deterministic two-level CSR build (no global atomics) ================
__global__ __launch_bounds__(1024) void k_count(
    const int* __restrict__ dst, int* __restrict__ rowcnt, int E, int NB, int es){
  __shared__ int h[1024];
  int blk = blockIdx.x;
  for (int i = threadIdx.x; i < NB; i += 1024) h[i] = 0;
  __syncthreads();
  int e0 = blk * es, e1 = min(e0 + es, E);
  for (int e = e0 + threadIdx.x; e < e1; e += 1024)
    atomicAdd(&h[dst[e] >> BSHIFT], 1);
  __syncthreads();
  for (int i = threadIdx.x; i < NB; i += 1024)
    rowcnt[blk * NB + i] = h[i];
}

__global__ __launch_bounds__(1024) void k_colscan(
    int* __restrict__ rowcnt, int* __restrict__ bbase, int NB, int nblk){
  int b = threadIdx.x;
  int total = 0;
  if (b < NB)
    for (int r = 0; r < nblk; r++) total += rowcnt[r * NB + b];
  int lane = b & 63, w = b >> 6;
  int x = total;
  #pragma unroll
  for (int d = 1; d < 64; d <<= 1){ int y = __shfl_up(x, d, 64); if (lane >= d) x += y; }
  __shared__ int tmp[16];
  if (lane == 63) tmp[w] = x;
  __syncthreads();
  if (b < 64){
    int s = (lane < 16) ? tmp[lane] : 0;
    #pragma unroll
    for (int d = 1; d < 16; d <<= 1){ int y = __shfl_up(s, d, 64); if (lane >= d) s += y; }
    if (lane < 16) tmp[lane] = s;
  }
  __syncthreads();
  int base = ((w > 0) ? tmp[w - 1] : 0) + x - total;  // exclusive
  if (b < NB){
    bbase[b] = base;
    int acc = base;
    for (int r = 0; r < nblk; r++){
      int v = rowcnt[r * NB + b];
      rowcnt[r * NB + b] = acc;
      acc += v;
    }
    if (b == NB - 1) bbase[NB] = acc;
  }
}

__global__ __launch_bounds__(1024) void k_place(
    const int* __restrict__ src, const int* __restrict__ dst,
    const int* __restrict__ rowcnt, uint* __restrict__ binned, int E, int NB, int es){
  __shared__ int cur[1024];
  int blk = blockIdx.x;
  for (int i = threadIdx.x; i < NB; i += 1024) cur[i] = rowcnt[blk * NB + i];
  __syncthreads();
  int e0 = blk * es, e1 = min(e0 + es, E);
  for (int e = e0 + threadIdx.x; e < e1; e += 1024){
    int d = dst[e];
    int b = d >> BSHIFT;
    int pos = atomicAdd(&cur[b], 1);
    binned[pos] = ((uint)src[e] << BSHIFT) | (uint)(d & 127);
  }
}

__global__ __launch_bounds__(256) void k_bpass(
    const uint* __restrict__ binned, const int* __restrict__ bbase,
    int* __restrict__ csr, int* __restrict__ offs, int* __restrict__ cnt, int N){
  int b = blockIdx.x;
  int n0 = b << BSHIFT;
  int tid = threadIdx.x;
  __shared__ int lcnt[128], loffs[128];
  if (tid < 128) lcnt[tid] = 0;
  __syncthreads();
  int base = bbase[b];
  int m = bbase[b + 1] - base;
  const uint* bp = binned + base;
  uint vv[12]; int slot[12];
  #pragma unroll
  for (int u = 0; u < 12; u++){
    int i = tid + u * 256;
    if (i < m){
      uint v = bp[i];
      vv[u] = v;
      slot[u] = atomicAdd(&lcnt[v & 127], 1);
    }
  }
  __syncthreads();
  if (tid < 64){
    int a0 = lcnt[tid * 2], a1 = lcnt[tid * 2 + 1];
    int s = a0 + a1;
    int x = s;
    #pragma unroll
    for (int d = 1; d < 64; d <<= 1){ int y = __shfl_up(x, d, 64); if (tid >= d) x += y; }
    int excl = x - s;
    loffs[tid * 2] = excl;
    loffs[tid * 2 + 1] = excl + a0;
  }
  __syncthreads();
  if (tid < 128 && n0 + tid < N){
    cnt[n0 + tid] = lcnt[tid];
    offs[n0 + tid] = base + loffs[tid];
  }
  #pragma unroll
  for (int u = 0; u < 12; u++){
    int i = tid + u * 256;
    if (i < m){
      uint v = vv[u];
      csr[base + loffs[v & 127] + slot[u]] = (int)(v >> BSHIFT);
    }
  }
}

// ---------------- scatter-mean aggregation v5 (pattern-BW floor ~3.5 TB/s) ----
__global__ __launch_bounds__(256) void k_aggregate(
    const ushort* __restrict__ x, const int* __restrict__ csr,
    const int* __restrict__ offs, const int* __restrict__ cnt,
    ushort* __restrict__ agg, int N){
  int node = blockIdx.x * 4 + (threadIdx.x >> 6);
  int lane = threadIdx.x & 63;
  if (node >= N) return;
  int grp = lane >> 4;       // which edge of the 4-group
  int l16 = lane & 15;       // 16B chunk within the row (8 features)
  uint lb  = (uint)(l16 << 4);
  int beg = offs[node], d = cnt[node];
  if (d == 0){
    if (grp == 0){
      uint4 z = {0u, 0u, 0u, 0u};
      *(uint4*)(agg + (size_t)node * HID + l16 * 8) = z;
    }
    return;
  }
  const int* __restrict__ cp = csr + beg;
  const char* __restrict__ xb = (const char*)x;
  f32x2 s0 = {0.f,0.f}, s1 = {0.f,0.f}, s2 = {0.f,0.f}, s3 = {0.f,0.f};
  int i = 0;
  for (; i + 8 <= d; i += 8){
    uint o0 = ((uint)cp[i + grp] << 8) + lb;
    uint o1 = ((uint)cp[i + 4 + grp] << 8) + lb;
    uint4 v0 = *(const uint4*)(xb + o0);
    uint4 v1 = *(const uint4*)(xb + o1);
    f32x2 t;
    t.x = u2f(v0.x << 16); t.y = u2f(v0.x & 0xffff0000u); s0 += t;
    t.x = u2f(v0.y << 16); t.y = u2f(v0.y & 0xffff0000u); s1 += t;
    t.x = u2f(v0.z << 16); t.y = u2f(v0.z & 0xffff0000u); s2 += t;
    t.x = u2f(v0.w << 16); t.y = u2f(v0.w & 0xffff0000u); s3 += t;
    t.x = u2f(v1.x << 16); t.y = u2f(v1.x & 0xffff0000u); s0 += t;
    t.x = u2f(v1.y << 16); t.y = u2f(v1.y & 0xffff0000u); s1 += t;
    t.x = u2f(v1.z << 16); t.y = u2f(v1.z & 0xffff0000u); s2 += t;
    t.x = u2f(v1.w << 16); t.y = u2f(v1.w & 0xffff0000u); s3 += t;
  }
  if (i < d){
    int p0 = i + grp, p1 = i + 4 + grp;
    bool k0 = p0 < d, k1 = p1 < d;
    uint o0 = ((uint)cp[k0 ? p0 : d - 1] << 8) + lb;
    uint o1 = ((uint)cp[k1 ? p1 : d - 1] << 8) + lb;
    uint4 v0 = *(const uint4*)(xb + o0);
    uint4 v1 = *(const uint4*)(xb + o1);
    uint ax, ay, az, aw;
    ax = k0 ? v0.x : 0u; ay = k0 ? v0.y : 0u; az = k0 ? v0.z : 0u; aw = k0 ? v0.w : 0u;
    f32x2 t;
    t.x = u2f(ax << 16); t.y = u2f(ax & 0xffff0000u); s0 += t;
    t.x = u2f(ay << 16); t.y = u2f(ay & 0xffff0000u); s1 += t;
    t.x = u2f(az << 16); t.y = u2f(az & 0xffff0000u); s2 += t;
    t.x = u2f(aw << 16); t.y = u2f(aw & 0xffff0000u); s3 += t;
    ax = k1 ? v1.x : 0u; ay = k1 ? v1.y : 0u; az = k1 ? v1.z : 0u; aw = k1 ? v1.w : 0u;
    t.x = u2f(ax << 16); t.y = u2f(ax & 0xffff0000u); s0 += t;
    t.x = u2f(ay << 16); t.y = u2f(ay & 0xffff0000u); s1 += t;
    t.x = u2f(az << 16); t.y = u2f(az & 0xffff0000u); s2 += t;
    t.x = u2f(aw << 16); t.y = u2f(aw & 0xffff0000u); s3 += t;
  }
  #pragma unroll
  for (int m = 16; m < 64; m <<= 1){
    s0.x += __shfl_xor(s0.x, m, 64); s0.y += __shfl_xor(s0.y, m, 64);
    s1.x += __shfl_xor(s1.x, m, 64); s1.y += __shfl_xor(s1.y, m, 64);
    s2.x += __shfl_xor(s2.x, m, 64); s2.y += __shfl_xor(s2.y, m, 64);
    s3.x += __shfl_xor(s3.x, m, 64); s3.y += __shfl_xor(s3.y, m, 64);
  }
  if (grp == 0){
    float inv = 1.0f / fmaxf((float)d, 1.0f);
    uint4 o;
    o.x = (uint)f2bf(s0.x * inv) | ((uint)f2bf(s0.y * inv) << 16);
    o.y = (uint)f2bf(s1.x * inv) | ((uint)f2bf(s1.y * inv) << 16);
    o.z = (uint)f2bf(s2.x * inv) | ((uint)f2bf(s2.y * inv) << 16);
    o.w = (uint)f2bf(s3.x * inv) | ((uint)f2bf(s3.y * inv) << 16);
    *(uint4*)(agg + (size_t)node * HID + l16 * 8) = o;
  }
}

// ---------------- fused dual-GEMM + bias + LN + ReLU + residual ----------------
// R11: 64-row blocks (128 threads, 2 independent waves) for finer CU load
// balance -- 1563 blocks @ ~6.1/CU (tail ~14%) vs 782 @ 3.05/CU (tail ~31%).
// Per-wave code identical to the proven R6/R9 kernel; no LDS, no barriers.
template<int HAS_RES>
__global__ __launch_bounds__(128, 4) void k_layer(
    const ushort* __restrict__ agg, const ushort* __restrict__ xin,
    const ushort* __restrict__ Wf,     // [kt4][mat2][jt8][lane64][8] bf16 (col-permuted)
    const float* __restrict__ bl, const float* __restrict__ gamma,
    const float* __restrict__ beta,
    ushort* __restrict__ xout, int N){
  int tid = threadIdx.x;
  int wv = tid >> 6, lane = tid & 63;
  int quad = lane >> 4, l16 = lane & 15;
  int rowbase = blockIdx.x * 64 + wv * 32;
  int r0 = rowbase + l16;      if (r0 >= N) r0 = N - 1;
  int r1 = rowbase + 16 + l16; if (r1 >= N) r1 = N - 1;
  int aq = quad * 8;

  const ushort* pa0 = agg + (size_t)r0 * HID;
  const ushort* pa1 = agg + (size_t)r1 * HID;
  const ushort* px0 = xin + (size_t)r0 * HID;
  const ushort* px1 = xin + (size_t)r1 * HID;

  f32x4 acc[2][8];
  {
    float4 bi0 = *(const float4*)(bl + l16 * 8);
    float4 bi1 = *(const float4*)(bl + l16 * 8 + 4);
    float bia[8] = {bi0.x, bi0.y, bi0.z, bi0.w, bi1.x, bi1.y, bi1.z, bi1.w};
    #pragma unroll
    for (int jt = 0; jt < 8; jt++){
      float b = bia[jt];
      f32x4 c = {b, b, b, b};
      acc[0][jt] = c; acc[1][jt] = c;
    }
  }

  bf16x8 c0 = load8(pa0 + aq), c1 = load8(pa1 + aq);
  bf16x8 c2 = load8(px0 + aq), c3 = load8(px1 + aq);
  #pragma unroll
  for (int kt = 0; kt < 4; kt++){
    bf16x8 n0 = c0, n1 = c1, n2 = c2, n3 = c3;
    if (kt < 3){
      int ao = (kt + 1) * 32 + aq;
      n0 = load8(pa0 + ao); n1 = load8(pa1 + ao);
      n2 = load8(px0 + ao); n3 = load8(px1 + ao);
    }
    #pragma unroll
    for (int jt = 0; jt < 8; jt++){
      bf16x8 bL = load8(Wf + ((kt * 16 + jt) * 64 + lane) * 8);
      bf16x8 bR = load8(Wf + ((kt * 16 + 8 + jt) * 64 + lane) * 8);
      acc[0][jt] = __builtin_amdgcn_mfma_f32_16x16x32_bf16(c0, bL, acc[0][jt], 0, 0, 0);
      acc[1][jt] = __builtin_amdgcn_mfma_f32_16x16x32_bf16(c1, bL, acc[1][jt], 0, 0, 0);
      acc[0][jt] = __builtin_amdgcn_mfma_f32_16x16x32_bf16(c2, bR, acc[0][jt], 0, 0, 0);
      acc[1][jt] = __builtin_amdgcn_mfma_f32_16x16x32_bf16(c3, bR, acc[1][jt], 0, 0, 0);
    }
    c0 = n0; c1 = n1; c2 = n2; c3 = n3;
  }

  // epilogue: constants loaded here (not live across the MFMA loop)
  float4 g0 = *(const float4*)(gamma + l16 * 8);
  float4 g1 = *(const float4*)(gamma + l16 * 8 + 4);
  float4 be0 = *(const float4*)(beta + l16 * 8);
  float4 be1 = *(const float4*)(beta + l16 * 8 + 4);
  float gg[8] = {g0.x, g0.y, g0.z, g0.w, g1.x, g1.y, g1.z, g1.w};
  float bb[8] = {be0.x, be0.y, be0.z, be0.w, be1.x, be1.y, be1.z, be1.w};

  #pragma unroll
  for (int rt = 0; rt < 2; rt++){
    float s1[4] = {0,0,0,0}, s2[4] = {0,0,0,0};
    #pragma unroll
    for (int jt = 0; jt < 8; jt++){
      #pragma unroll
      for (int r = 0; r < 4; r++){ float v = acc[rt][jt][r]; s1[r] += v; s2[r] += v * v; }
    }
    #pragma unroll
    for (int m = 1; m < 16; m <<= 1){
      #pragma unroll
      for (int r = 0; r < 4; r++){
        s1[r] += __shfl_xor(s1[r], m, 64);
        s2[r] += __shfl_xor(s2[r], m, 64);
      }
    }
    #pragma unroll
    for (int r = 0; r < 4; r++){
      float mu = s1[r] * (1.f / 128.f);
      float var = s2[r] * (1.f / 128.f) - mu * mu;
      float rs = rsqrtf(var + 1e-5f);
      int row = rowbase + rt * 16 + quad * 4 + r;
      int rowc = row < N ? row : N - 1;
      uint rw[4] = {0u, 0u, 0u, 0u};
      if (HAS_RES){
        uint4 rv = *(const uint4*)(xin + (size_t)rowc * HID + l16 * 8);
        rw[0] = rv.x; rw[1] = rv.y; rw[2] = rv.z; rw[3] = rv.w;
      }
      uint ow[4];
      #pragma unroll
      for (int p = 0; p < 4; p++){
        float v0 = (acc[rt][2 * p][r] - mu) * rs * gg[2 * p] + bb[2 * p];
        float v1 = (acc[rt][2 * p + 1][r] - mu) * rs * gg[2 * p + 1] + bb[2 * p + 1];
        v0 = fmaxf(v0, 0.f);
        v1 = fmaxf(v1, 0.f);
        if (HAS_RES){
          v0 += bf2f((ushort)(rw[p] & 0xffffu));
          v1 += bf2f((ushort)(rw[p] >> 16));
        }
        ow[p] = (uint)f2bf(v0) | ((uint)f2bf(v1) << 16);
      }
      uint4 o;
      o.x = ow[0]; o.y = ow[1]; o.z = ow[2]; o.w = ow[3];
      if (row < N)
        *(uint4*)(xout + (size_t)row * HID + l16 * 8) = o;
    }
  }
}

// ---------------- JK: out = [emb,x1,x2,x3] @ jkW^T + jkb  (out f32) ----------------
// R11: same 64-row retile; per-wave code identical to R6/R9.
__global__ __launch_bounds__(128, 4) void k_jk(
    const ushort* __restrict__ emb, const ushort* __restrict__ x1,
    const ushort* __restrict__ x2, const ushort* __restrict__ x3,
    const ushort* __restrict__ Wf,   // [kt16][jt8][lane64][8] bf16 (col-permuted)
    const float* __restrict__ jkb, float* __restrict__ out, int N){
  int tid = threadIdx.x;
  int wv = tid >> 6, lane = tid & 63;
  int quad = lane >> 4, l16 = lane & 15;
  int rowbase = blockIdx.x * 64 + wv * 32;
  int r0 = rowbase + l16;      if (r0 >= N) r0 = N - 1;
  int r1 = rowbase + 16 + l16; if (r1 >= N) r1 = N - 1;
  int aq = quad * 8;
  size_t o0 = (size_t)r0 * HID, o1 = (size_t)r1 * HID;

  f32x4 acc[2][8];
  #pragma unroll
  for (int jt = 0; jt < 8; jt++){
    f32x4 z = {0.f, 0.f, 0.f, 0.f};
    acc[0][jt] = z; acc[1][jt] = z;
  }

  const ushort* srcs[4] = {emb, x1, x2, x3};
  bf16x8 a0 = load8(emb + o0 + aq);
  bf16x8 a1 = load8(emb + o1 + aq);
  #pragma unroll
  for (int ktg = 0; ktg < 16; ktg++){
    bf16x8 n0 = a0, n1 = a1;
    if (ktg < 15){
      const ushort* sp = srcs[(ktg + 1) >> 2];   // compile-time after unroll
      int ao = ((ktg + 1) & 3) * 32 + aq;
      n0 = load8(sp + o0 + ao);
      n1 = load8(sp + o1 + ao);
    }
    #pragma unroll
    for (int jt = 0; jt < 8; jt++){
      bf16x8 bW = load8(Wf + ((ktg * 8 + jt) * 64 + lane) * 8);
      acc[0][jt] = __builtin_amdgcn_mfma_f32_16x16x32_bf16(a0, bW, acc[0][jt], 0, 0, 0);
      acc[1][jt] = __builtin_amdgcn_mfma_f32_16x16x32_bf16(a1, bW, acc[1][jt], 0, 0, 0);
    }
    a0 = n0; a1 = n1;
  }

  float4 jb0 = *(const float4*)(jkb + l16 * 4);
  float4 jb1 = *(const float4*)(jkb + 64 + l16 * 4);
  float bia[8] = {jb0.x, jb0.y, jb0.z, jb0.w, jb1.x, jb1.y, jb1.z, jb1.w};

  #pragma unroll
  for (int rt = 0; rt < 2; rt++){
    #pragma unroll
    for (int r = 0; r < 4; r++){
      int row = rowbase + rt * 16 + quad * 4 + r;
      if (row < N){
        f32x4 v0 = {acc[rt][0][r] + bia[0], acc[rt][1][r] + bia[1],
                    acc[rt][2][r] + bia[2], acc[rt][3][r] + bia[3]};
        f32x4 v1 = {acc[rt][4][r] + bia[4], acc[rt][5][r] + bia[5],
                    acc[rt][6][r] + bia[6], acc[rt][7][r] + bia[7]};
        *(f32x4*)(out + (size_t)row * HID + l16 * 4) = v0;
        *(f32x4*)(out + (size_t)row * HID + 64 + l16 * 4) = v1;
      }
    }
  }
}

extern "C" void kernel_launch(void* const* d_in, const int* in_sizes, int n_in,
                              void* d_out, int out_size, void* d_ws, size_t ws_size,
                              hipStream_t stream){
  const float* emb   = (const float*)d_in[0];
  const float* Wl    = (const float*)d_in[1];
  const float* bl    = (const float*)d_in[2];
  const float* Wr    = (const float*)d_in[3];
  const float* gamma = (const float*)d_in[4];
  const float* beta  = (const float*)d_in[5];
  const float* jkW   = (const float*)d_in[6];
  const float* jkb   = (const float*)d_in[7];
  const int*   eidx  = (const int*)d_in[8];
  int N = in_sizes[0] / HID;
  int E = in_sizes[8] / 2;
  const int* src = eidx;
  const int* dst = eidx + E;
  float* out = (float*)d_out;

  int NB = (N + 127) >> BSHIFT;        // coarse buckets of 128 nodes
  int es = (E + NBLK - 1) / NBLK;      // edges per slice block

  // workspace carve (256B aligned)
  char* w = (char*)d_ws;
  auto carve = [&](size_t bytes) -> char* {
    char* p = w; w += (bytes + 255) & ~(size_t)255; return p;
  };
  int Npad = ((N + 127) / 128) * 128;
  int* rowcnt   = (int*)carve((size_t)NBLK * NB * 4);
  int* bbase    = (int*)carve((size_t)(NB + 1) * 4);
  uint* binned  = (uint*)carve((size_t)E * 4);
  int* cnt      = (int*)carve((size_t)N * 4);
  int* offs     = (int*)carve((size_t)N * 4);
  int* csr      = (int*)carve((size_t)E * 4);
  ushort* Wfrag = (ushort*)carve((size_t)3 * 32768 * 2);
  ushort* jkWf  = (ushort*)carve((size_t)65536 * 2);
  ushort* embbf = (ushort*)carve((size_t)Npad * HID * 2);
  ushort* agg   = (ushort*)carve((size_t)Npad * HID * 2);
  ushort* x1    = (ushort*)carve((size_t)Npad * HID * 2);
  ushort* x2    = (ushort*)carve((size_t)Npad * HID * 2);
  ushort* x3    = (ushort*)carve((size_t)Npad * HID * 2);

  // merged weight transforms + emb cast (one launch)
  int nEmb = N * HID;
  int nCvt = 163840 + nEmb;
  k_cvtall<<<(nCvt + 255) / 256, 256, 0, stream>>>(emb, Wl, Wr, jkW,
                                                   embbf, Wfrag, jkWf, nEmb);

  // deterministic two-level CSR build
  k_count<<<NBLK, 1024, 0, stream>>>(dst, rowcnt, E, NB, es);
  k_colscan<<<1, 1024, 0, stream>>>(rowcnt, bbase, NB, NBLK);
  k_place<<<NBLK, 1024, 0, stream>>>(src, dst, rowcnt, binned, E, NB, es);
  k_bpass<<<NB, 256, 0, stream>>>(binned, bbase, csr, offs, cnt, N);

  int aggBlocks = (N + 3) / 4;
  int gemmBlocks = (N + 63) / 64;     // one 64-row tile (2 waves) per block

  // layer 0 (no residual)
  k_aggregate<<<aggBlocks, 256, 0, stream>>>(embbf, csr, offs, cnt, agg, N);
  k_layer<0><<<gemmBlocks, 128, 0, stream>>>(agg, embbf, Wfrag, bl, gamma, beta, x1, N);
  // layer 1
  k_aggregate<<<aggBlocks, 256, 0, stream>>>(x1, csr, offs, cnt, agg, N);
  k_layer<1><<<gemmBlocks, 128, 0, stream>>>(agg, x1, Wfrag + 32768, bl + HID,
                                             gamma + HID, beta + HID, x2, N);
  // layer 2
  k_aggregate<<<aggBlocks, 256, 0, stream>>>(x2, csr, offs, cnt, agg, N);
  k_layer<1><<<gemmBlocks, 128, 0, stream>>>(agg, x2, Wfrag + 2 * 32768, bl + 2 * HID,
                                             gamma + 2 * HID, beta + 2 * HID, x3, N);
  // jumping knowledge projection
  k_jk<<<gemmBlocks, 128, 0, stream>>>(embbf, x1, x2, x3, jkWf, jkb, out, N);
}